// Round 10
// baseline (405.814 us; speedup 1.0000x reference)
//
#include <hip/hip_runtime.h>

#define NND 50000
#define NED 800000
#define NF  128
#define NH  64
#define BN_EPS 1e-5
#define NCOPY 64   // stats slot-copies
#define SCB  256   // scan chunk
#define NSB  ((NND + SCB - 1) / SCB)   // 196 scan blocks
#define XNODES (NND / 8)               // 6250 nodes per XCD slice
#define FCH  196                       // edge chunks (1024 int4 each) per XCD pass

// ---- workspace byte offsets (16B aligned) ----
#define WS_HB     0                          // bf16[NND*64]  (h, gather source)   6,400,000 B
#define WS_AGG    6400000                    // bf16[NND*64]  (agg, MLP input)     6,400,000 B
#define WS_STATS  12800000                   // double[NCOPY*128]  65,536 B (self-cleaned by k_fin)
#define WS_SSF    (WS_STATS + NCOPY*128*8)   // float[128]  scale|shift
#define WS_DEG    (WS_SSF + 512)             // int[NND]  (memset'd with stats+ssf)
#define WS_OFFS   (WS_DEG + NND*4)           // int[NND+4]
#define WS_CUR    (WS_OFFS + (NND+4)*4)      // int[NND]
#define WS_PARTS  (WS_CUR + NND*4)           // int[256]
#define WS_ESRC   (WS_PARTS + 256*4)         // int[NED]

// ---- bf16 helpers (storage-only; all math in f32) ----
__device__ __forceinline__ unsigned bfrn(float x) {          // f32 -> bf16 (RTN-even)
    unsigned u = __float_as_uint(x);
    return (u + 0x7fffu + ((u >> 16) & 1u)) >> 16;
}
__device__ __forceinline__ unsigned pk(float lo, float hi) { // 2x f32 -> packed bf16x2
    return bfrn(lo) | (bfrn(hi) << 16);
}
__device__ __forceinline__ void upadd(unsigned u, float& lo, float& hi) {
    lo += __uint_as_float(u << 16);
    hi += __uint_as_float(u & 0xffff0000u);
}
__device__ __forceinline__ float ulo(unsigned u) { return __uint_as_float(u << 16); }
__device__ __forceinline__ float uhi(unsigned u) { return __uint_as_float(u & 0xffff0000u); }

// ---------------- CSR build (XCD-partitioned) ----------------
__global__ __launch_bounds__(256) void k_deg(const int* __restrict__ dst,
                                             int* __restrict__ deg) {
    int xcd = blockIdx.x & 7;
    int chunk = blockIdx.x >> 3;
    int lo = xcd * XNODES;
    const int4* d4 = (const int4*)dst;
#pragma unroll
    for (int r = 0; r < 4; ++r) {
        int i = chunk * 1024 + r * 256 + threadIdx.x;
        if (i < NED / 4) {
            int4 d = d4[i];
            if ((unsigned)(d.x - lo) < XNODES) atomicAdd(&deg[d.x], 1);
            if ((unsigned)(d.y - lo) < XNODES) atomicAdd(&deg[d.y], 1);
            if ((unsigned)(d.z - lo) < XNODES) atomicAdd(&deg[d.z], 1);
            if ((unsigned)(d.w - lo) < XNODES) atomicAdd(&deg[d.w], 1);
        }
    }
}

__global__ __launch_bounds__(256) void k_fill(const int* __restrict__ src,
                                              const int* __restrict__ dst,
                                              int* __restrict__ cur,
                                              int* __restrict__ esrc) {
    int xcd = blockIdx.x & 7;
    int chunk = blockIdx.x >> 3;
    int lo = xcd * XNODES;
    const int4* d4 = (const int4*)dst;
#pragma unroll
    for (int r = 0; r < 4; ++r) {
        int i = chunk * 1024 + r * 256 + threadIdx.x;
        if (i < NED / 4) {
            int4 d = d4[i];
            int e = i * 4;
            if ((unsigned)(d.x - lo) < XNODES) esrc[atomicAdd(&cur[d.x], 1)] = src[e];
            if ((unsigned)(d.y - lo) < XNODES) esrc[atomicAdd(&cur[d.y], 1)] = src[e + 1];
            if ((unsigned)(d.z - lo) < XNODES) esrc[atomicAdd(&cur[d.z], 1)] = src[e + 2];
            if ((unsigned)(d.w - lo) < XNODES) esrc[atomicAdd(&cur[d.w], 1)] = src[e + 3];
        }
    }
}

__global__ __launch_bounds__(SCB) void k_part(const int* __restrict__ deg,
                                              int* __restrict__ offs,
                                              int* __restrict__ parts) {
    __shared__ int sd[SCB];
    int t = threadIdx.x;
    int i = blockIdx.x * SCB + t;
    int v = (i < NND) ? deg[i] : 0;
    sd[t] = v;
    __syncthreads();
#pragma unroll
    for (int off = 1; off < SCB; off <<= 1) {
        int u = (t >= off) ? sd[t - off] : 0;
        __syncthreads();
        sd[t] += u;
        __syncthreads();
    }
    if (i < NND) offs[i] = sd[t] - v;
    if (t == SCB - 1) parts[blockIdx.x] = sd[t];
}

__global__ __launch_bounds__(256) void k_scan2(int* __restrict__ parts) {
    __shared__ int sd[256];
    int t = threadIdx.x;
    int v = (t < NSB) ? parts[t] : 0;
    sd[t] = v;
    __syncthreads();
#pragma unroll
    for (int off = 1; off < 256; off <<= 1) {
        int u = (t >= off) ? sd[t - off] : 0;
        __syncthreads();
        sd[t] += u;
        __syncthreads();
    }
    if (t < NSB) parts[t] = sd[t] - v;
}

__global__ __launch_bounds__(256) void k_apply(int* __restrict__ offs,
                                               const int* __restrict__ parts,
                                               int* __restrict__ cur) {
    int i = blockIdx.x * 256 + threadIdx.x;
    if (i < NND) {
        int o = offs[i] + parts[i >> 8];
        offs[i] = o;
        cur[i] = o;
    }
    if (i == NND) offs[NND] = NED;
}

// ---------------- BN finalize: reduce slot-copies -> float sc/sh; self-clean ----------------
__global__ void k_fin(double* __restrict__ st,
                      const float* __restrict__ g, const float* __restrict__ b,
                      float* __restrict__ ssout) {
    int c = threadIdx.x;   // 64 threads
    double sum = 0.0, ssq = 0.0;
#pragma unroll
    for (int cp = 0; cp < NCOPY; ++cp) {
        sum += st[cp * 128 + c];
        ssq += st[cp * 128 + 64 + c];
    }
#pragma unroll
    for (int cp = 0; cp < NCOPY; ++cp) {
        st[cp * 128 + c] = 0.0;
        st[cp * 128 + 64 + c] = 0.0;
    }
    double mu  = sum / (double)NND;
    double var = ssq / (double)NND - mu * mu;
    if (var < 0.0) var = 0.0;
    double rs = 1.0 / sqrt(var + BN_EPS);
    double sc = (double)g[c] * rs;
    ssout[c]      = (float)sc;
    ssout[64 + c] = (float)((double)b[c] - mu * sc);
}

// ---------------- input transform: wave-per-tile 8x8 GEMM, writes bf16 h ----------------
__global__ __launch_bounds__(128) void k_transform(const float* __restrict__ x,
                                                   const float* __restrict__ Wt,
                                                   const float* __restrict__ bt,
                                                   uint4* __restrict__ hB4,
                                                   double* __restrict__ stats) {
    __shared__ __align__(16) float Wl[NF * NH];        // 32 KB
    __shared__ __align__(16) float sTbuf[2 * 64 * 68]; // 2 x 17.4 KB
    int tid  = threadIdx.x;
    int wave = tid >> 6, lane = tid & 63;
    int ti = lane & 7, tj = lane >> 3;
    int tile = blockIdx.x * 2 + wave;                  // 0..781
    int base = tile * 64;
    float* sTw = &sTbuf[wave * 64 * 68];
    const float4* x4 = (const float4*)x;

#pragma unroll
    for (int r = 0; r < 16; ++r) {
        int i4 = r * 128 + tid;
        ((float4*)Wl)[i4] = ((const float4*)Wt)[i4];
    }

    float acc[8][8];
#pragma unroll
    for (int i = 0; i < 8; ++i)
#pragma unroll
        for (int j = 0; j < 8; ++j) acc[i][j] = 0.f;

    for (int ch = 0; ch < 2; ++ch) {
        __syncthreads();
#pragma unroll
        for (int s = 0; s < 16; ++s) {
            int flat = s * 64 + lane;
            int nl = flat >> 4, q = flat & 15;
            float4 v = {0.f, 0.f, 0.f, 0.f};
            if (base + nl < NND) v = x4[(size_t)(base + nl) * 32 + ch * 16 + q];
            sTw[(q * 4 + 0) * 68 + nl] = v.x;
            sTw[(q * 4 + 1) * 68 + nl] = v.y;
            sTw[(q * 4 + 2) * 68 + nl] = v.z;
            sTw[(q * 4 + 3) * 68 + nl] = v.w;
        }
        __syncthreads();
#pragma unroll 2
        for (int k = 0; k < 64; ++k) {
            const float* ap = &sTw[k * 68 + ti * 8];
            float4 alo = *(const float4*)ap;
            float4 ahi = *(const float4*)(ap + 4);
            const float* wp = &Wl[(ch * 64 + k) * NH + tj * 8];
            float4 wlo = *(const float4*)wp;
            float4 whi = *(const float4*)(wp + 4);
            float a8[8] = {alo.x, alo.y, alo.z, alo.w, ahi.x, ahi.y, ahi.z, ahi.w};
            float w8[8] = {wlo.x, wlo.y, wlo.z, wlo.w, whi.x, whi.y, whi.z, whi.w};
#pragma unroll
            for (int i = 0; i < 8; ++i)
#pragma unroll
                for (int j = 0; j < 8; ++j) acc[i][j] += a8[i] * w8[j];
        }
    }

    float b8[8];
    *(float4*)&b8[0] = ((const float4*)bt)[tj * 2];
    *(float4*)&b8[4] = ((const float4*)bt)[tj * 2 + 1];

    float s8[8], q8[8];
#pragma unroll
    for (int j = 0; j < 8; ++j) { s8[j] = 0.f; q8[j] = 0.f; }
#pragma unroll
    for (int i = 0; i < 8; ++i) {
        int n = base + ti * 8 + i;
        if (n < NND) {
            float o[8];
#pragma unroll
            for (int j = 0; j < 8; ++j) {
                o[j] = acc[i][j] + b8[j];
                s8[j] += o[j];
                q8[j] += o[j] * o[j];
            }
            uint4 ov;
            ov.x = pk(o[0], o[1]); ov.y = pk(o[2], o[3]);
            ov.z = pk(o[4], o[5]); ov.w = pk(o[6], o[7]);
            hB4[(size_t)n * 8 + tj] = ov;
        }
    }
#pragma unroll
    for (int m = 1; m < 8; m <<= 1) {
#pragma unroll
        for (int j = 0; j < 8; ++j) {
            s8[j] += __shfl_xor(s8[j], m);
            q8[j] += __shfl_xor(q8[j], m);
        }
    }
    if (ti == 0) {
        int slot = (tile & (NCOPY - 1)) * 128 + tj * 8;
#pragma unroll
        for (int j = 0; j < 8; ++j) {
            atomicAdd(&stats[slot + j], (double)s8[j]);
            atomicAdd(&stats[slot + 64 + j], (double)q8[j]);
        }
    }
}

// ---------------- aggregation: wave-per-node, bf16 rows (128B), 8 rows in flight ----------------
// aggB = bf16( sc*(self + sum_nbrs) + (deg+1)*sh ), accumulation in f32
__global__ __launch_bounds__(256) void k_agg(const uint4* __restrict__ hB4,
                                             uint4* __restrict__ aggB4,
                                             const float* __restrict__ ss,
                                             const int* __restrict__ offs,
                                             const int* __restrict__ esrc) {
    int tid  = threadIdx.x;
    int lane = tid & 63;
    int wv   = tid >> 6;
    int n = blockIdx.x * 4 + wv;
    int q = lane & 7;        // 16B sub-block within 128B row (cols q*8 .. q*8+7)
    int r = lane >> 3;       // edge slot 0..7

    int e0 = offs[n], e1 = offs[n + 1];
    int deg = e1 - e0;

    float a[8];
#pragma unroll
    for (int i = 0; i < 8; ++i) a[i] = 0.f;

    if (r == 0) {            // self row (8 lanes cover the 128B row)
        uint4 u = hB4[(size_t)n * 8 + q];
        upadd(u.x, a[0], a[1]); upadd(u.y, a[2], a[3]);
        upadd(u.z, a[4], a[5]); upadd(u.w, a[6], a[7]);
    }

    for (int bb = e0; bb < e1; bb += 64) {
        int m = e1 - bb; if (m > 64) m = 64;
        int idx = (lane < m) ? esrc[bb + lane] : 0;
        int t = 0;
        for (; t + 32 <= m; t += 32) {          // 32 edges, 4KB in flight per wave
            int j0 = __shfl(idx, t + r);
            int j1 = __shfl(idx, t + 8 + r);
            int j2 = __shfl(idx, t + 16 + r);
            int j3 = __shfl(idx, t + 24 + r);
            uint4 u0 = hB4[(size_t)j0 * 8 + q];
            uint4 u1 = hB4[(size_t)j1 * 8 + q];
            uint4 u2 = hB4[(size_t)j2 * 8 + q];
            uint4 u3 = hB4[(size_t)j3 * 8 + q];
            upadd(u0.x, a[0], a[1]); upadd(u0.y, a[2], a[3]);
            upadd(u0.z, a[4], a[5]); upadd(u0.w, a[6], a[7]);
            upadd(u1.x, a[0], a[1]); upadd(u1.y, a[2], a[3]);
            upadd(u1.z, a[4], a[5]); upadd(u1.w, a[6], a[7]);
            upadd(u2.x, a[0], a[1]); upadd(u2.y, a[2], a[3]);
            upadd(u2.z, a[4], a[5]); upadd(u2.w, a[6], a[7]);
            upadd(u3.x, a[0], a[1]); upadd(u3.y, a[2], a[3]);
            upadd(u3.z, a[4], a[5]); upadd(u3.w, a[6], a[7]);
        }
        for (; t < m; t += 8) {                 // 8-edge tail, predicated
            int e = t + r;
            int j = __shfl(idx, e & 63);
            if (e < m) {
                uint4 u = hB4[(size_t)j * 8 + q];
                upadd(u.x, a[0], a[1]); upadd(u.y, a[2], a[3]);
                upadd(u.z, a[4], a[5]); upadd(u.w, a[6], a[7]);
            }
        }
    }

    // reduce across the 8 edge slots (lane bits 3,4,5); q preserved
#pragma unroll
    for (int msk = 8; msk <= 32; msk <<= 1)
#pragma unroll
        for (int i = 0; i < 8; ++i) a[i] += __shfl_xor(a[i], msk);

    if (r == 0) {
        float4 scA = ((const float4*)ss)[q * 2];
        float4 scB = ((const float4*)ss)[q * 2 + 1];
        float4 shA = ((const float4*)(ss + 64))[q * 2];
        float4 shB = ((const float4*)(ss + 64))[q * 2 + 1];
        float dn = (float)(deg + 1);
        float r0 = scA.x * a[0] + dn * shA.x;
        float r1 = scA.y * a[1] + dn * shA.y;
        float r2 = scA.z * a[2] + dn * shA.z;
        float r3 = scA.w * a[3] + dn * shA.w;
        float r4 = scB.x * a[4] + dn * shB.x;
        float r5 = scB.y * a[5] + dn * shB.y;
        float r6 = scB.z * a[6] + dn * shB.z;
        float r7 = scB.w * a[7] + dn * shB.w;
        uint4 ov;
        ov.x = pk(r0, r1); ov.y = pk(r2, r3); ov.z = pk(r4, r5); ov.w = pk(r6, r7);
        aggB4[(size_t)n * 8 + q] = ov;
    }
}

// ---------------- MLP: wave-per-tile 8x8 GEMM x2, bf16 in, bf16 and/or f32 out ----------------
__global__ __launch_bounds__(128) void k_mlp(const uint4* __restrict__ aggB4,
                                             float* __restrict__ outF,    // f32 out (last layer) or null
                                             uint4* __restrict__ hBo,     // bf16 out or null
                                             double* __restrict__ statsout,
                                             const float* __restrict__ W1,
                                             const float* __restrict__ W2) {
    __shared__ __align__(16) float W1l[NH * NH];       // 16 KB
    __shared__ __align__(16) float W2l[NH * NH];       // 16 KB
    __shared__ __align__(16) float sTbuf[2 * 64 * 68]; // 2 x 17.4 KB
    int tid  = threadIdx.x;
    int wave = tid >> 6, lane = tid & 63;
    int ti = lane & 7, tj = lane >> 3;
    int tile = blockIdx.x * 2 + wave;
    int base = tile * 64;
    float* sTw = &sTbuf[wave * 64 * 68];

#pragma unroll
    for (int r = 0; r < 8; ++r) {
        int i4 = r * 128 + tid;
        ((float4*)W1l)[i4] = ((const float4*)W1)[i4];
        ((float4*)W2l)[i4] = ((const float4*)W2)[i4];
    }
    // stage own tile transposed (bf16 -> f32), 512 uint4 per tile
#pragma unroll
    for (int s = 0; s < 8; ++s) {
        int i4 = s * 64 + lane;
        int nl = i4 >> 3, q = i4 & 7;
        uint4 u = make_uint4(0u, 0u, 0u, 0u);
        if (base + nl < NND) u = aggB4[(size_t)(base + nl) * 8 + q];
        sTw[(q * 8 + 0) * 68 + nl] = ulo(u.x);
        sTw[(q * 8 + 1) * 68 + nl] = uhi(u.x);
        sTw[(q * 8 + 2) * 68 + nl] = ulo(u.y);
        sTw[(q * 8 + 3) * 68 + nl] = uhi(u.y);
        sTw[(q * 8 + 4) * 68 + nl] = ulo(u.z);
        sTw[(q * 8 + 5) * 68 + nl] = uhi(u.z);
        sTw[(q * 8 + 6) * 68 + nl] = ulo(u.w);
        sTw[(q * 8 + 7) * 68 + nl] = uhi(u.w);
    }
    __syncthreads();

    float acc[8][8];
#pragma unroll
    for (int i = 0; i < 8; ++i)
#pragma unroll
        for (int j = 0; j < 8; ++j) acc[i][j] = 0.f;
#pragma unroll 2
    for (int k = 0; k < 64; ++k) {
        const float* ap = &sTw[k * 68 + ti * 8];
        float4 alo = *(const float4*)ap;
        float4 ahi = *(const float4*)(ap + 4);
        const float* wp = &W1l[k * NH + tj * 8];
        float4 wlo = *(const float4*)wp;
        float4 whi = *(const float4*)(wp + 4);
        float a8[8] = {alo.x, alo.y, alo.z, alo.w, ahi.x, ahi.y, ahi.z, ahi.w};
        float w8[8] = {wlo.x, wlo.y, wlo.z, wlo.w, whi.x, whi.y, whi.z, whi.w};
#pragma unroll
        for (int i = 0; i < 8; ++i)
#pragma unroll
            for (int j = 0; j < 8; ++j) acc[i][j] += a8[i] * w8[j];
    }
#pragma unroll
    for (int i = 0; i < 8; ++i)
#pragma unroll
        for (int j = 0; j < 8; ++j) acc[i][j] = fmaxf(acc[i][j], 0.f);

    __syncthreads();
#pragma unroll
    for (int j = 0; j < 8; ++j) {
        float* p = &sTw[(tj * 8 + j) * 68 + ti * 8];
        float4 lo = {acc[0][j], acc[1][j], acc[2][j], acc[3][j]};
        float4 hi = {acc[4][j], acc[5][j], acc[6][j], acc[7][j]};
        *(float4*)p = lo;
        *(float4*)(p + 4) = hi;
    }
    __syncthreads();

    float a2[8][8];
#pragma unroll
    for (int i = 0; i < 8; ++i)
#pragma unroll
        for (int j = 0; j < 8; ++j) a2[i][j] = 0.f;
#pragma unroll 2
    for (int k = 0; k < 64; ++k) {
        const float* ap = &sTw[k * 68 + ti * 8];
        float4 alo = *(const float4*)ap;
        float4 ahi = *(const float4*)(ap + 4);
        const float* wp = &W2l[k * NH + tj * 8];
        float4 wlo = *(const float4*)wp;
        float4 whi = *(const float4*)(wp + 4);
        float a8[8] = {alo.x, alo.y, alo.z, alo.w, ahi.x, ahi.y, ahi.z, ahi.w};
        float w8[8] = {wlo.x, wlo.y, wlo.z, wlo.w, whi.x, whi.y, whi.z, whi.w};
#pragma unroll
        for (int i = 0; i < 8; ++i)
#pragma unroll
            for (int j = 0; j < 8; ++j) a2[i][j] += a8[i] * w8[j];
    }

    float s8[8], q8[8];
#pragma unroll
    for (int j = 0; j < 8; ++j) { s8[j] = 0.f; q8[j] = 0.f; }
#pragma unroll
    for (int i = 0; i < 8; ++i) {
        int n = base + ti * 8 + i;
        if (n < NND) {
            float o[8];
#pragma unroll
            for (int j = 0; j < 8; ++j) {
                o[j] = fmaxf(a2[i][j], 0.f);
                s8[j] += o[j];
                q8[j] += o[j] * o[j];
            }
            if (outF) {
                *(float4*)&outF[(size_t)n * NH + tj * 8]     = *(float4*)&o[0];
                *(float4*)&outF[(size_t)n * NH + tj * 8 + 4] = *(float4*)&o[4];
            }
            if (hBo) {
                uint4 ov;
                ov.x = pk(o[0], o[1]); ov.y = pk(o[2], o[3]);
                ov.z = pk(o[4], o[5]); ov.w = pk(o[6], o[7]);
                hBo[(size_t)n * 8 + tj] = ov;
            }
        }
    }
#pragma unroll
    for (int m = 1; m < 8; m <<= 1) {
#pragma unroll
        for (int j = 0; j < 8; ++j) {
            s8[j] += __shfl_xor(s8[j], m);
            q8[j] += __shfl_xor(q8[j], m);
        }
    }
    if (ti == 0) {
        int slot = (tile & (NCOPY - 1)) * 128 + tj * 8;
#pragma unroll
        for (int j = 0; j < 8; ++j) {
            atomicAdd(&statsout[slot + j], (double)s8[j]);
            atomicAdd(&statsout[slot + 64 + j], (double)q8[j]);
        }
    }
}

// ---------------- final BN apply, in-place on f32 out ----------------
__global__ void k_bnout(float* __restrict__ h, const float* __restrict__ ss) {
    int i4 = blockIdx.x * 256 + threadIdx.x;
    if (i4 < NND * NH / 4) {
        int cg = i4 & 15;
        float4 v   = ((float4*)h)[i4];
        float4 scv = ((const float4*)ss)[cg];
        float4 shv = ((const float4*)(ss + 64))[cg];
        v.x = v.x * scv.x + shv.x;
        v.y = v.y * scv.y + shv.y;
        v.z = v.z * scv.z + shv.z;
        v.w = v.w * scv.w + shv.w;
        ((float4*)h)[i4] = v;
    }
}

extern "C" void kernel_launch(void* const* d_in, const int* in_sizes, int n_in,
                              void* d_out, int out_size, void* d_ws, size_t ws_size,
                              hipStream_t stream) {
    const float* x     = (const float*)d_in[0];
    const int*   ei    = (const int*)d_in[1];
    const float* Wt    = (const float*)d_in[2];
    const float* bt    = (const float*)d_in[3];
    const float* gt    = (const float*)d_in[4];
    const float* bbt   = (const float*)d_in[5];
    const float* W1    = (const float*)d_in[6];
    const float* W2    = (const float*)d_in[7];
    const float* gamma = (const float*)d_in[8];
    const float* beta  = (const float*)d_in[9];
    float* out = (float*)d_out;

    char* ws = (char*)d_ws;
    uint4*  hB    = (uint4*)(ws + WS_HB);
    uint4*  aggB  = (uint4*)(ws + WS_AGG);
    double* stats = (double*)(ws + WS_STATS);
    float*  ssf   = (float*)(ws + WS_SSF);
    int*    deg   = (int*)(ws + WS_DEG);
    int*    offs  = (int*)(ws + WS_OFFS);
    int*    cur   = (int*)(ws + WS_CUR);
    int*    parts = (int*)(ws + WS_PARTS);
    int*    esrc  = (int*)(ws + WS_ESRC);

    const int* srcv = ei;
    const int* dstv = ei + NED;

    // one memset covers stats + ssf + deg (contiguous)
    hipMemsetAsync(stats, 0, NCOPY * 128 * 8 + 512 + NND * 4, stream);

    const int PGRID = FCH * 8;   // 1568 blocks: 8 XCD slices x 196 edge chunks
    k_deg<<<PGRID, 256, 0, stream>>>(dstv, deg);
    k_part<<<NSB, SCB, 0, stream>>>(deg, offs, parts);
    k_scan2<<<1, 256, 0, stream>>>(parts);
    k_apply<<<NSB, 256, 0, stream>>>(offs, parts, cur);
    k_fill<<<PGRID, 256, 0, stream>>>(srcv, dstv, cur, esrc);

    const int NT2 = 391;            // 782 tiles / 2 waves per block
    const int NB  = NND / 4;        // 12500 agg blocks

    k_transform<<<NT2, 128, 0, stream>>>(x, Wt, bt, hB, stats);
    k_fin<<<1, 64, 0, stream>>>(stats, gt, bbt, ssf);

    // layer 0
    k_agg<<<NB, 256, 0, stream>>>(hB, aggB, ssf, offs, esrc);
    k_mlp<<<NT2, 128, 0, stream>>>(aggB, nullptr, hB, stats, W1, W2);
    k_fin<<<1, 64, 0, stream>>>(stats, gamma, beta, ssf);

    // layer 1
    k_agg<<<NB, 256, 0, stream>>>(hB, aggB, ssf, offs, esrc);
    k_mlp<<<NT2, 128, 0, stream>>>(aggB, nullptr, hB, stats, W1 + 4096, W2 + 4096);
    k_fin<<<1, 64, 0, stream>>>(stats, gamma + 64, beta + 64, ssf);

    // layer 2: f32 out for final BN
    k_agg<<<NB, 256, 0, stream>>>(hB, aggB, ssf, offs, esrc);
    k_mlp<<<NT2, 128, 0, stream>>>(aggB, out, nullptr, stats, W1 + 8192, W2 + 8192);
    k_fin<<<1, 64, 0, stream>>>(stats, gamma + 128, beta + 128, ssf);

    k_bnout<<<(NND * NH / 4 + 255) / 256, 256, 0, stream>>>(out, ssf);
}

// Round 11
// 311.557 us; speedup vs baseline: 1.3025x; 1.3025x over previous
//
#include <hip/hip_runtime.h>

#define NND 50000
#define NED 800000
#define NF  128
#define NH  64
#define BN_EPS 1e-5
#define NCOPY 8    // stats slot-copies (f32; 782/8 ~ 98 writers per address)
#define SCB  256   // scan chunk
#define NSB  ((NND + SCB - 1) / SCB)   // 196 scan blocks
#define XNODES (NND / 8)               // 6250 nodes per XCD slice
#define FCH  196                       // edge chunks (1024 int4 each) per XCD pass

// ---- workspace byte offsets (16B aligned) ----
#define WS_HB     0                          // bf16[NND*64]  (h, gather source)   6,400,000 B
#define WS_AGG    6400000                    // bf16[NND*64]  (agg, MLP input)     6,400,000 B
#define WS_STATS  12800000                   // float[NCOPY*128]  4,096 B (self-cleaned by k_fin)
#define WS_SSF    (WS_STATS + NCOPY*128*4)   // float[128]  scale|shift
#define WS_DEG    (WS_SSF + 512)             // int[NND]  (memset'd with stats+ssf)
#define WS_OFFS   (WS_DEG + NND*4)           // int[NND+4]
#define WS_CUR    (WS_OFFS + (NND+4)*4)      // int[NND]
#define WS_PARTS  (WS_CUR + NND*4)           // int[256]
#define WS_ESRC   (WS_PARTS + 256*4)         // int[NED]

// ---- bf16 helpers (storage-only; all math in f32) ----
__device__ __forceinline__ unsigned bfrn(float x) {          // f32 -> bf16 (RTN-even)
    unsigned u = __float_as_uint(x);
    return (u + 0x7fffu + ((u >> 16) & 1u)) >> 16;
}
__device__ __forceinline__ unsigned pk(float lo, float hi) { // 2x f32 -> packed bf16x2
    return bfrn(lo) | (bfrn(hi) << 16);
}
__device__ __forceinline__ void upadd(unsigned u, float& lo, float& hi) {
    lo += __uint_as_float(u << 16);
    hi += __uint_as_float(u & 0xffff0000u);
}
__device__ __forceinline__ float ulo(unsigned u) { return __uint_as_float(u << 16); }
__device__ __forceinline__ float uhi(unsigned u) { return __uint_as_float(u & 0xffff0000u); }

// ---------------- CSR build (XCD-partitioned) ----------------
__global__ __launch_bounds__(256) void k_deg(const int* __restrict__ dst,
                                             int* __restrict__ deg) {
    int xcd = blockIdx.x & 7;
    int chunk = blockIdx.x >> 3;
    int lo = xcd * XNODES;
    const int4* d4 = (const int4*)dst;
#pragma unroll
    for (int r = 0; r < 4; ++r) {
        int i = chunk * 1024 + r * 256 + threadIdx.x;
        if (i < NED / 4) {
            int4 d = d4[i];
            if ((unsigned)(d.x - lo) < XNODES) atomicAdd(&deg[d.x], 1);
            if ((unsigned)(d.y - lo) < XNODES) atomicAdd(&deg[d.y], 1);
            if ((unsigned)(d.z - lo) < XNODES) atomicAdd(&deg[d.z], 1);
            if ((unsigned)(d.w - lo) < XNODES) atomicAdd(&deg[d.w], 1);
        }
    }
}

__global__ __launch_bounds__(256) void k_fill(const int* __restrict__ src,
                                              const int* __restrict__ dst,
                                              int* __restrict__ cur,
                                              int* __restrict__ esrc) {
    int xcd = blockIdx.x & 7;
    int chunk = blockIdx.x >> 3;
    int lo = xcd * XNODES;
    const int4* d4 = (const int4*)dst;
#pragma unroll
    for (int r = 0; r < 4; ++r) {
        int i = chunk * 1024 + r * 256 + threadIdx.x;
        if (i < NED / 4) {
            int4 d = d4[i];
            int e = i * 4;
            if ((unsigned)(d.x - lo) < XNODES) esrc[atomicAdd(&cur[d.x], 1)] = src[e];
            if ((unsigned)(d.y - lo) < XNODES) esrc[atomicAdd(&cur[d.y], 1)] = src[e + 1];
            if ((unsigned)(d.z - lo) < XNODES) esrc[atomicAdd(&cur[d.z], 1)] = src[e + 2];
            if ((unsigned)(d.w - lo) < XNODES) esrc[atomicAdd(&cur[d.w], 1)] = src[e + 3];
        }
    }
}

__global__ __launch_bounds__(SCB) void k_part(const int* __restrict__ deg,
                                              int* __restrict__ offs,
                                              int* __restrict__ parts) {
    __shared__ int sd[SCB];
    int t = threadIdx.x;
    int i = blockIdx.x * SCB + t;
    int v = (i < NND) ? deg[i] : 0;
    sd[t] = v;
    __syncthreads();
#pragma unroll
    for (int off = 1; off < SCB; off <<= 1) {
        int u = (t >= off) ? sd[t - off] : 0;
        __syncthreads();
        sd[t] += u;
        __syncthreads();
    }
    if (i < NND) offs[i] = sd[t] - v;
    if (t == SCB - 1) parts[blockIdx.x] = sd[t];
}

__global__ __launch_bounds__(256) void k_scan2(int* __restrict__ parts) {
    __shared__ int sd[256];
    int t = threadIdx.x;
    int v = (t < NSB) ? parts[t] : 0;
    sd[t] = v;
    __syncthreads();
#pragma unroll
    for (int off = 1; off < 256; off <<= 1) {
        int u = (t >= off) ? sd[t - off] : 0;
        __syncthreads();
        sd[t] += u;
        __syncthreads();
    }
    if (t < NSB) parts[t] = sd[t] - v;
}

__global__ __launch_bounds__(256) void k_apply(int* __restrict__ offs,
                                               const int* __restrict__ parts,
                                               int* __restrict__ cur) {
    int i = blockIdx.x * 256 + threadIdx.x;
    if (i < NND) {
        int o = offs[i] + parts[i >> 8];
        offs[i] = o;
        cur[i] = o;
    }
    if (i == NND) offs[NND] = NED;
}

// ---------------- BN finalize: reduce f32 slot-copies -> sc/sh; self-clean ----------------
__global__ void k_fin(float* __restrict__ st,
                      const float* __restrict__ g, const float* __restrict__ b,
                      float* __restrict__ ssout) {
    int c = threadIdx.x;   // 64 threads
    float sum = 0.f, ssq = 0.f;
    for (int cp = 0; cp < NCOPY; ++cp) {
        sum += st[cp * 128 + c];
        ssq += st[cp * 128 + 64 + c];
    }
    for (int cp = 0; cp < NCOPY; ++cp) {
        st[cp * 128 + c] = 0.f;
        st[cp * 128 + 64 + c] = 0.f;
    }
    double mu  = (double)sum / (double)NND;
    double var = (double)ssq / (double)NND - mu * mu;
    if (var < 0.0) var = 0.0;
    double rs = 1.0 / sqrt(var + BN_EPS);
    double sc = (double)g[c] * rs;
    ssout[c]      = (float)sc;
    ssout[64 + c] = (float)((double)b[c] - mu * sc);
}

// ---------------- input transform: col-split 1-tile blocks (2 waves, acc 8x4) ----------------
__global__ __launch_bounds__(128) void k_transform(const float* __restrict__ x,
                                                   const float* __restrict__ Wt,
                                                   const float* __restrict__ bt,
                                                   unsigned* __restrict__ hB,
                                                   float* __restrict__ stats) {
    __shared__ __align__(16) float Wl[NF * NH];   // 32 KB
    __shared__ __align__(16) float sT[64 * 68];   // 17.4 KB (shared by both waves)
    int tid  = threadIdx.x;
    int wave = tid >> 6, lane = tid & 63;
    int ti = lane & 7, tj = lane >> 3;            // 8 node-rows x 8 col-quads
    int tile = blockIdx.x;                        // 0..781
    int base = tile * 64;
    const float4* x4 = (const float4*)x;

#pragma unroll
    for (int r = 0; r < 16; ++r) {
        int i4 = r * 128 + tid;
        ((float4*)Wl)[i4] = ((const float4*)Wt)[i4];
    }

    float acc[8][4];
#pragma unroll
    for (int i = 0; i < 8; ++i)
#pragma unroll
        for (int j = 0; j < 4; ++j) acc[i][j] = 0.f;

    int cw = wave * 32 + tj * 4;                  // this lane's 4 output cols

    for (int ch = 0; ch < 2; ++ch) {
        __syncthreads();
        // stage x[:, ch*64 .. +63] transposed: 1024 float4 by 128 threads
#pragma unroll
        for (int s = 0; s < 8; ++s) {
            int flat = s * 128 + tid;
            int nl = flat >> 4, q = flat & 15;
            float4 v = {0.f, 0.f, 0.f, 0.f};
            if (base + nl < NND) v = x4[(size_t)(base + nl) * 32 + ch * 16 + q];
            sT[(q * 4 + 0) * 68 + nl] = v.x;
            sT[(q * 4 + 1) * 68 + nl] = v.y;
            sT[(q * 4 + 2) * 68 + nl] = v.z;
            sT[(q * 4 + 3) * 68 + nl] = v.w;
        }
        __syncthreads();
#pragma unroll 4
        for (int k = 0; k < 64; ++k) {
            const float* ap = &sT[k * 68 + ti * 8];
            float4 alo = *(const float4*)ap;
            float4 ahi = *(const float4*)(ap + 4);
            float4 wv  = *(const float4*)&Wl[(ch * 64 + k) * NH + cw];
            float a8[8] = {alo.x, alo.y, alo.z, alo.w, ahi.x, ahi.y, ahi.z, ahi.w};
            float w4[4] = {wv.x, wv.y, wv.z, wv.w};
#pragma unroll
            for (int i = 0; i < 8; ++i)
#pragma unroll
                for (int j = 0; j < 4; ++j) acc[i][j] += a8[i] * w4[j];
        }
    }

    float4 bv = *(const float4*)&bt[cw];
    float bj[4] = {bv.x, bv.y, bv.z, bv.w};

    float s4[4] = {0.f, 0.f, 0.f, 0.f}, q4[4] = {0.f, 0.f, 0.f, 0.f};
    uint2* hB2 = (uint2*)hB;
#pragma unroll
    for (int i = 0; i < 8; ++i) {
        int n = base + ti * 8 + i;
        if (n < NND) {
            float o[4];
#pragma unroll
            for (int j = 0; j < 4; ++j) {
                o[j] = acc[i][j] + bj[j];
                s4[j] += o[j];
                q4[j] += o[j] * o[j];
            }
            uint2 ov; ov.x = pk(o[0], o[1]); ov.y = pk(o[2], o[3]);
            hB2[(size_t)n * 16 + wave * 8 + tj] = ov;
        }
    }
#pragma unroll
    for (int m = 1; m < 8; m <<= 1) {
#pragma unroll
        for (int j = 0; j < 4; ++j) {
            s4[j] += __shfl_xor(s4[j], m);
            q4[j] += __shfl_xor(q4[j], m);
        }
    }
    if (ti == 0) {
        int slot = (tile & (NCOPY - 1)) * 128;
#pragma unroll
        for (int j = 0; j < 4; ++j) {
            atomicAdd(&stats[slot + cw + j], s4[j]);
            atomicAdd(&stats[slot + 64 + cw + j], q4[j]);
        }
    }
}

// ---------------- aggregation: wave-per-node, bf16 rows (128B), 8 rows in flight ----------------
__global__ __launch_bounds__(256) void k_agg(const uint4* __restrict__ hB4,
                                             uint4* __restrict__ aggB4,
                                             const float* __restrict__ ss,
                                             const int* __restrict__ offs,
                                             const int* __restrict__ esrc) {
    int tid  = threadIdx.x;
    int lane = tid & 63;
    int wv   = tid >> 6;
    int n = blockIdx.x * 4 + wv;
    int q = lane & 7;        // 16B sub-block within 128B row
    int r = lane >> 3;       // edge slot 0..7

    int e0 = offs[n], e1 = offs[n + 1];
    int deg = e1 - e0;

    float a[8];
#pragma unroll
    for (int i = 0; i < 8; ++i) a[i] = 0.f;

    if (r == 0) {
        uint4 u = hB4[(size_t)n * 8 + q];
        upadd(u.x, a[0], a[1]); upadd(u.y, a[2], a[3]);
        upadd(u.z, a[4], a[5]); upadd(u.w, a[6], a[7]);
    }

    for (int bb = e0; bb < e1; bb += 64) {
        int m = e1 - bb; if (m > 64) m = 64;
        int idx = (lane < m) ? esrc[bb + lane] : 0;
        int t = 0;
        for (; t + 32 <= m; t += 32) {
            int j0 = __shfl(idx, t + r);
            int j1 = __shfl(idx, t + 8 + r);
            int j2 = __shfl(idx, t + 16 + r);
            int j3 = __shfl(idx, t + 24 + r);
            uint4 u0 = hB4[(size_t)j0 * 8 + q];
            uint4 u1 = hB4[(size_t)j1 * 8 + q];
            uint4 u2 = hB4[(size_t)j2 * 8 + q];
            uint4 u3 = hB4[(size_t)j3 * 8 + q];
            upadd(u0.x, a[0], a[1]); upadd(u0.y, a[2], a[3]);
            upadd(u0.z, a[4], a[5]); upadd(u0.w, a[6], a[7]);
            upadd(u1.x, a[0], a[1]); upadd(u1.y, a[2], a[3]);
            upadd(u1.z, a[4], a[5]); upadd(u1.w, a[6], a[7]);
            upadd(u2.x, a[0], a[1]); upadd(u2.y, a[2], a[3]);
            upadd(u2.z, a[4], a[5]); upadd(u2.w, a[6], a[7]);
            upadd(u3.x, a[0], a[1]); upadd(u3.y, a[2], a[3]);
            upadd(u3.z, a[4], a[5]); upadd(u3.w, a[6], a[7]);
        }
        for (; t < m; t += 8) {
            int e = t + r;
            int j = __shfl(idx, e & 63);
            if (e < m) {
                uint4 u = hB4[(size_t)j * 8 + q];
                upadd(u.x, a[0], a[1]); upadd(u.y, a[2], a[3]);
                upadd(u.z, a[4], a[5]); upadd(u.w, a[6], a[7]);
            }
        }
    }

#pragma unroll
    for (int msk = 8; msk <= 32; msk <<= 1)
#pragma unroll
        for (int i = 0; i < 8; ++i) a[i] += __shfl_xor(a[i], msk);

    if (r == 0) {
        float4 scA = ((const float4*)ss)[q * 2];
        float4 scB = ((const float4*)ss)[q * 2 + 1];
        float4 shA = ((const float4*)(ss + 64))[q * 2];
        float4 shB = ((const float4*)(ss + 64))[q * 2 + 1];
        float dn = (float)(deg + 1);
        float r0 = scA.x * a[0] + dn * shA.x;
        float r1 = scA.y * a[1] + dn * shA.y;
        float r2 = scA.z * a[2] + dn * shA.z;
        float r3 = scA.w * a[3] + dn * shA.w;
        float r4 = scB.x * a[4] + dn * shB.x;
        float r5 = scB.y * a[5] + dn * shB.y;
        float r6 = scB.z * a[6] + dn * shB.z;
        float r7 = scB.w * a[7] + dn * shB.w;
        uint4 ov;
        ov.x = pk(r0, r1); ov.y = pk(r2, r3); ov.z = pk(r4, r5); ov.w = pk(r6, r7);
        aggB4[(size_t)n * 8 + q] = ov;
    }
}

// ---------------- MLP: col-split 1-tile blocks (2 waves, acc 8x4), 2 GEMMs ----------------
__global__ __launch_bounds__(128) void k_mlp(const uint4* __restrict__ aggB4,
                                             float* __restrict__ outF,    // f32 out (last layer) or null
                                             unsigned* __restrict__ hBo,  // bf16 out or null
                                             float* __restrict__ stats,
                                             const float* __restrict__ W1,
                                             const float* __restrict__ W2) {
    __shared__ __align__(16) float W1l[NH * NH];  // 16 KB
    __shared__ __align__(16) float W2l[NH * NH];  // 16 KB
    __shared__ __align__(16) float sT[64 * 68];   // 17.4 KB (agg, then t1)
    int tid  = threadIdx.x;
    int wave = tid >> 6, lane = tid & 63;
    int ti = lane & 7, tj = lane >> 3;
    int tile = blockIdx.x;
    int base = tile * 64;
    int cw = wave * 32 + tj * 4;

#pragma unroll
    for (int r = 0; r < 8; ++r) {
        int i4 = r * 128 + tid;
        ((float4*)W1l)[i4] = ((const float4*)W1)[i4];
        ((float4*)W2l)[i4] = ((const float4*)W2)[i4];
    }
    // stage agg tile transposed (bf16 -> f32): 512 uint4 by 128 threads
#pragma unroll
    for (int s = 0; s < 4; ++s) {
        int i4 = s * 128 + tid;
        int nl = i4 >> 3, q = i4 & 7;
        uint4 u = make_uint4(0u, 0u, 0u, 0u);
        if (base + nl < NND) u = aggB4[(size_t)(base + nl) * 8 + q];
        sT[(q * 8 + 0) * 68 + nl] = ulo(u.x);
        sT[(q * 8 + 1) * 68 + nl] = uhi(u.x);
        sT[(q * 8 + 2) * 68 + nl] = ulo(u.y);
        sT[(q * 8 + 3) * 68 + nl] = uhi(u.y);
        sT[(q * 8 + 4) * 68 + nl] = ulo(u.z);
        sT[(q * 8 + 5) * 68 + nl] = uhi(u.z);
        sT[(q * 8 + 6) * 68 + nl] = ulo(u.w);
        sT[(q * 8 + 7) * 68 + nl] = uhi(u.w);
    }
    __syncthreads();

    // GEMM1: t1[:, cw..cw+3] = relu(agg @ W1)
    float a1[8][4];
#pragma unroll
    for (int i = 0; i < 8; ++i)
#pragma unroll
        for (int j = 0; j < 4; ++j) a1[i][j] = 0.f;
#pragma unroll 4
    for (int k = 0; k < 64; ++k) {
        const float* ap = &sT[k * 68 + ti * 8];
        float4 alo = *(const float4*)ap;
        float4 ahi = *(const float4*)(ap + 4);
        float4 wv  = *(const float4*)&W1l[k * NH + cw];
        float a8[8] = {alo.x, alo.y, alo.z, alo.w, ahi.x, ahi.y, ahi.z, ahi.w};
        float w4[4] = {wv.x, wv.y, wv.z, wv.w};
#pragma unroll
        for (int i = 0; i < 8; ++i)
#pragma unroll
            for (int j = 0; j < 4; ++j) a1[i][j] += a8[i] * w4[j];
    }
#pragma unroll
    for (int i = 0; i < 8; ++i)
#pragma unroll
        for (int j = 0; j < 4; ++j) a1[i][j] = fmaxf(a1[i][j], 0.f);

    __syncthreads();
    // transpose-write t1 into sT[col][node] (waves write disjoint cols)
#pragma unroll
    for (int j = 0; j < 4; ++j) {
        float* p = &sT[(cw + j) * 68 + ti * 8];
        float4 lo = {a1[0][j], a1[1][j], a1[2][j], a1[3][j]};
        float4 hi = {a1[4][j], a1[5][j], a1[6][j], a1[7][j]};
        *(float4*)p = lo;
        *(float4*)(p + 4) = hi;
    }
    __syncthreads();

    // GEMM2: out[:, cw..cw+3] = relu(t1 @ W2)
    float a2[8][4];
#pragma unroll
    for (int i = 0; i < 8; ++i)
#pragma unroll
        for (int j = 0; j < 4; ++j) a2[i][j] = 0.f;
#pragma unroll 4
    for (int k = 0; k < 64; ++k) {
        const float* ap = &sT[k * 68 + ti * 8];
        float4 alo = *(const float4*)ap;
        float4 ahi = *(const float4*)(ap + 4);
        float4 wv  = *(const float4*)&W2l[k * NH + cw];
        float a8[8] = {alo.x, alo.y, alo.z, alo.w, ahi.x, ahi.y, ahi.z, ahi.w};
        float w4[4] = {wv.x, wv.y, wv.z, wv.w};
#pragma unroll
        for (int i = 0; i < 8; ++i)
#pragma unroll
            for (int j = 0; j < 4; ++j) a2[i][j] += a8[i] * w4[j];
    }

    float s4[4] = {0.f, 0.f, 0.f, 0.f}, q4[4] = {0.f, 0.f, 0.f, 0.f};
    uint2* hBo2 = (uint2*)hBo;
#pragma unroll
    for (int i = 0; i < 8; ++i) {
        int n = base + ti * 8 + i;
        if (n < NND) {
            float o[4];
#pragma unroll
            for (int j = 0; j < 4; ++j) {
                o[j] = fmaxf(a2[i][j], 0.f);
                s4[j] += o[j];
                q4[j] += o[j] * o[j];
            }
            if (outF) *(float4*)&outF[(size_t)n * NH + cw] = *(float4*)&o[0];
            if (hBo) {
                uint2 ov; ov.x = pk(o[0], o[1]); ov.y = pk(o[2], o[3]);
                hBo2[(size_t)n * 16 + wave * 8 + tj] = ov;
            }
        }
    }
#pragma unroll
    for (int m = 1; m < 8; m <<= 1) {
#pragma unroll
        for (int j = 0; j < 4; ++j) {
            s4[j] += __shfl_xor(s4[j], m);
            q4[j] += __shfl_xor(q4[j], m);
        }
    }
    if (ti == 0) {
        int slot = (tile & (NCOPY - 1)) * 128;
#pragma unroll
        for (int j = 0; j < 4; ++j) {
            atomicAdd(&stats[slot + cw + j], s4[j]);
            atomicAdd(&stats[slot + 64 + cw + j], q4[j]);
        }
    }
}

// ---------------- final BN apply, in-place on f32 out ----------------
__global__ void k_bnout(float* __restrict__ h, const float* __restrict__ ss) {
    int i4 = blockIdx.x * 256 + threadIdx.x;
    if (i4 < NND * NH / 4) {
        int cg = i4 & 15;
        float4 v   = ((float4*)h)[i4];
        float4 scv = ((const float4*)ss)[cg];
        float4 shv = ((const float4*)(ss + 64))[cg];
        v.x = v.x * scv.x + shv.x;
        v.y = v.y * scv.y + shv.y;
        v.z = v.z * scv.z + shv.z;
        v.w = v.w * scv.w + shv.w;
        ((float4*)h)[i4] = v;
    }
}

extern "C" void kernel_launch(void* const* d_in, const int* in_sizes, int n_in,
                              void* d_out, int out_size, void* d_ws, size_t ws_size,
                              hipStream_t stream) {
    const float* x     = (const float*)d_in[0];
    const int*   ei    = (const int*)d_in[1];
    const float* Wt    = (const float*)d_in[2];
    const float* bt    = (const float*)d_in[3];
    const float* gt    = (const float*)d_in[4];
    const float* bbt   = (const float*)d_in[5];
    const float* W1    = (const float*)d_in[6];
    const float* W2    = (const float*)d_in[7];
    const float* gamma = (const float*)d_in[8];
    const float* beta  = (const float*)d_in[9];
    float* out = (float*)d_out;

    char* ws = (char*)d_ws;
    unsigned* hB    = (unsigned*)(ws + WS_HB);
    unsigned* aggB  = (unsigned*)(ws + WS_AGG);
    float*    stats = (float*)(ws + WS_STATS);
    float*    ssf   = (float*)(ws + WS_SSF);
    int*      deg   = (int*)(ws + WS_DEG);
    int*      offs  = (int*)(ws + WS_OFFS);
    int*      cur   = (int*)(ws + WS_CUR);
    int*      parts = (int*)(ws + WS_PARTS);
    int*      esrc  = (int*)(ws + WS_ESRC);

    const int* srcv = ei;
    const int* dstv = ei + NED;

    // one memset covers stats + ssf + deg (contiguous)
    hipMemsetAsync(stats, 0, NCOPY * 128 * 4 + 512 + NND * 4, stream);

    const int PGRID = FCH * 8;   // 1568 blocks: 8 XCD slices x 196 edge chunks
    k_deg<<<PGRID, 256, 0, stream>>>(dstv, deg);
    k_part<<<NSB, SCB, 0, stream>>>(deg, offs, parts);
    k_scan2<<<1, 256, 0, stream>>>(parts);
    k_apply<<<NSB, 256, 0, stream>>>(offs, parts, cur);
    k_fill<<<PGRID, 256, 0, stream>>>(srcv, dstv, cur, esrc);

    const int NT = 782;             // one 64-node tile per block
    const int NB = NND / 4;         // 12500 agg blocks

    k_transform<<<NT, 128, 0, stream>>>(x, Wt, bt, hB, stats);
    k_fin<<<1, 64, 0, stream>>>(stats, gt, bbt, ssf);

    // layer 0
    k_agg<<<NB, 256, 0, stream>>>((const uint4*)hB, (uint4*)aggB, ssf, offs, esrc);
    k_mlp<<<NT, 128, 0, stream>>>((const uint4*)aggB, nullptr, hB, stats, W1, W2);
    k_fin<<<1, 64, 0, stream>>>(stats, gamma, beta, ssf);

    // layer 1
    k_agg<<<NB, 256, 0, stream>>>((const uint4*)hB, (uint4*)aggB, ssf, offs, esrc);
    k_mlp<<<NT, 128, 0, stream>>>((const uint4*)aggB, nullptr, hB, stats, W1 + 4096, W2 + 4096);
    k_fin<<<1, 64, 0, stream>>>(stats, gamma + 64, beta + 64, ssf);

    // layer 2: f32 out for final BN
    k_agg<<<NB, 256, 0, stream>>>((const uint4*)hB, (uint4*)aggB, ssf, offs, esrc);
    k_mlp<<<NT, 128, 0, stream>>>((const uint4*)aggB, out, nullptr, stats, W1 + 8192, W2 + 8192);
    k_fin<<<1, 64, 0, stream>>>(stats, gamma + 128, beta + 128, ssf);

    k_bnout<<<(NND * NH / 4 + 255) / 256, 256, 0, stream>>>(out, ssf);
}